// Round 3
// baseline (321.863 us; speedup 1.0000x reference)
//
#include <hip/hip_runtime.h>

// Butterfly network: 12 stages over rows of 4096 fp32.
// y[p] <- W[s][p][0]*y[p] + W[s][p][1]*y[p^d],  d = 1<<s, s = 0..11
//
// One block (256 thr) processes RPB=4 rows entirely on-chip:
//   layout 1 (p = 16t+i)            -> stages 0..3 in registers
//   layout 2 (p = hi*256 + 16j+lo)  -> stages 4..7 in registers
//   layout 3 (p = 256k + t)         -> stages 8..11 in registers, coalesced store
//
// LDS is 32 KB (float2[4096] = row-PAIR packed); each transition runs twice
// (rows 0-1 then rows 2-3) with b64 LDS ops. 160/32 = 5 blocks/CU.
//
// Occupancy control (history):
//   (256,2) @64KB LDS: 88 VGPR, no spill, but 2 blocks/CU -> 21% occ, 127 us
//   (256,5): allocator collapsed to 48 VGPR, heavy spill  -> 213 us
//   (256,4): backend targeted range-max (8 waves/EU, 64 VGPR), spilled -> 154 us
// Fix: waves_per_eu(4,5) — max 5 matches the LDS ceiling (5 blocks/CU), so the
// allocator stops squeezing to 64; min 4 keeps the cap at 128 (> natural need).
// Plus: weights are loaded PER PAIR inside the butterfly loop (2 x float2 live,
// not ws[16] = 32 regs), cutting mandatory pressure to ~70-80 so 5 waves fit.
//
// Swizzle: position (P2,P1,P0) row-pair lives at float2 index
//     A2 = P2*256 + P0*16 + (P1 ^ P0)
// All four access patterns are bank-uniform (4 lanes per bank-pair = the
// throughput minimum for wave64 b64 ops):
//   T1 write (thread = [P2|P1], iter i=P0): A2 = hi*256 + i*16 + (lo^i)
//   T1 read  (thread = [P2|P0], iter j=P1): A2 = hi*256 + lo*16 + (j^lo)
//   T2 write (thread = [P2|P0], iter j=P1): same addresses as T1 read
//                                           -> thread-private, no barrier
//   T2 read  (thread = [P1|P0], iter k=P2): A2 = k*256 + lo*16 + (hi^lo)
// XOR terms land in ADDRESSES only; register indices stay compile-time.

constexpr int LROW = 4096;
constexpr int RPB  = 4;     // rows per block
constexpr int NBLK = 8192 / RPB;

__global__ __launch_bounds__(256)
__attribute__((amdgpu_waves_per_eu(4, 5)))
void butterfly12_kernel(const float* __restrict__ x,
                        const float* __restrict__ W,
                        float* __restrict__ out)
{
    __shared__ float2 lds[LROW];   // 32 KB

    const int t  = threadIdx.x;
    const int hi = t >> 4;         // P2 in layouts 1,2 ; P1 in layout 3
    const int lo = t & 15;         // P1 in layout 1 ; P0 in layouts 2,3
    const size_t row0 = (size_t)blockIdx.x * RPB;

    float v[RPB][16];

    // ---- load: layout 1, p = 16t + i, 4 x float4 per row ----
    #pragma unroll
    for (int r = 0; r < RPB; ++r) {
        const float4* xr = reinterpret_cast<const float4*>(x + (row0 + r) * LROW);
        #pragma unroll
        for (int m = 0; m < 4; ++m) {
            const float4 q = xr[t * 4 + m];
            v[r][4*m+0] = q.x; v[r][4*m+1] = q.y;
            v[r][4*m+2] = q.z; v[r][4*m+3] = q.w;
        }
    }

    // ---- phase 1: stages 0..3, p = 16t + i ----
    #pragma unroll
    for (int b = 0; b < 4; ++b) {
        const float* wb = W + ((size_t)b * LROW + 16 * t) * 2;
        const int dl = 1 << b;
        #pragma unroll
        for (int g = 0; g < 16; g += 2*dl)
            #pragma unroll
            for (int m = 0; m < dl; ++m) {
                const int a = g + m, c = a + dl;
                const float2 wa = *reinterpret_cast<const float2*>(wb + 2*a);
                const float2 wc = *reinterpret_cast<const float2*>(wb + 2*c);
                #pragma unroll
                for (int r = 0; r < RPB; ++r) {
                    const float va = v[r][a], vb = v[r][c];
                    v[r][a] = wa.x * va + wa.y * vb;
                    v[r][c] = wc.x * vb + wc.y * va;
                }
            }
    }

    // ---- transition 1 -> layout 2, row-pair at a time through 32 KB ----
    #pragma unroll
    for (int h = 0; h < 2; ++h) {
        if (h) __syncthreads();             // WAR: pair-0 reads done before overwrite
        #pragma unroll
        for (int i = 0; i < 16; ++i)
            lds[hi*256 + i*16 + (lo ^ i)] = make_float2(v[2*h][i], v[2*h+1][i]);
        __syncthreads();
        #pragma unroll
        for (int j = 0; j < 16; ++j) {
            const float2 q = lds[hi*256 + lo*16 + (j ^ lo)];
            v[2*h][j] = q.x; v[2*h+1][j] = q.y;
        }
    }

    // ---- phase 2: stages 4..7, p = hi*256 + 16j + lo ----
    #pragma unroll
    for (int b = 0; b < 4; ++b) {
        const float* wb = W + ((size_t)(4 + b) * LROW + hi*256 + lo) * 2;
        const int dl = 1 << b;
        #pragma unroll
        for (int g = 0; g < 16; g += 2*dl)
            #pragma unroll
            for (int m = 0; m < dl; ++m) {
                const int a = g + m, c = a + dl;
                const float2 wa = *reinterpret_cast<const float2*>(wb + 32*a);
                const float2 wc = *reinterpret_cast<const float2*>(wb + 32*c);
                #pragma unroll
                for (int r = 0; r < RPB; ++r) {
                    const float va = v[r][a], vb = v[r][c];
                    v[r][a] = wa.x * va + wa.y * vb;
                    v[r][c] = wc.x * vb + wc.y * va;
                }
            }
    }

    // ---- transition 2 -> layout 3, row-pair at a time ----
    // first write hits exactly the addresses this thread read in transition 1
    // (thread-private slot set => no barrier needed before it)
    #pragma unroll
    for (int h = 0; h < 2; ++h) {
        if (h) __syncthreads();
        #pragma unroll
        for (int j = 0; j < 16; ++j)
            lds[hi*256 + lo*16 + (j ^ lo)] = make_float2(v[2*h][j], v[2*h+1][j]);
        __syncthreads();
        const int slot = lo*16 + (hi ^ lo);
        #pragma unroll
        for (int k = 0; k < 16; ++k) {
            const float2 q = lds[k*256 + slot];
            v[2*h][k] = q.x; v[2*h+1][k] = q.y;
        }
    }

    // ---- phase 3: stages 8..11, p = 256k + t ----
    #pragma unroll
    for (int b = 0; b < 4; ++b) {
        const float* wb = W + ((size_t)(8 + b) * LROW + t) * 2;
        const int dl = 1 << b;
        #pragma unroll
        for (int g = 0; g < 16; g += 2*dl)
            #pragma unroll
            for (int m = 0; m < dl; ++m) {
                const int a = g + m, c = a + dl;
                const float2 wa = *reinterpret_cast<const float2*>(wb + 512*a);
                const float2 wc = *reinterpret_cast<const float2*>(wb + 512*c);
                #pragma unroll
                for (int r = 0; r < RPB; ++r) {
                    const float va = v[r][a], vb = v[r][c];
                    v[r][a] = wa.x * va + wa.y * vb;
                    v[r][c] = wc.x * vb + wc.y * va;
                }
            }
    }

    // ---- store: layout 3 => lane-consecutive dword stores, fully coalesced ----
    #pragma unroll
    for (int r = 0; r < RPB; ++r) {
        float* orow = out + (row0 + r) * LROW;
        #pragma unroll
        for (int k = 0; k < 16; ++k)
            orow[k*256 + t] = v[r][k];
    }
}

extern "C" void kernel_launch(void* const* d_in, const int* in_sizes, int n_in,
                              void* d_out, int out_size, void* d_ws, size_t ws_size,
                              hipStream_t stream) {
    const float* x = (const float*)d_in[0];   // (8192, 4096) fp32
    const float* W = (const float*)d_in[1];   // (12, 4096, 2) fp32
    float* out = (float*)d_out;               // (8192, 4096) fp32

    butterfly12_kernel<<<NBLK, 256, 0, stream>>>(x, W, out);
}

// Round 4
// 258.412 us; speedup vs baseline: 1.2455x; 1.2455x over previous
//
#include <hip/hip_runtime.h>

// Butterfly network: 12 stages over rows of 4096 fp32.
// y[p] <- W[s][p][0]*y[p] + W[s][p][1]*y[p^d],  d = 1<<s, s = 0..11
//
// Radix-8 decomposition: p = [P3|P2|P1|P0] (3 bits each).
// Block = 512 threads, RPB = 4 rows, 8 positions/thread -> v[4][8] = 32 VGPRs
// (designed to FIT the allocator's 64-VGPR / 8-waves-per-EU target; rounds 1-3
// proved it squeezes to 64 and spills whenever LDS permits high occupancy).
//
//   L1: p = 8t + i          (thread [P3P2P1], i=P0) -> stages 0..2
//   L2: p = t6*512+t3*64+8i+t0 (thread [P3P2P0], i=P1) -> stages 3..5
//   L3: p = t6*512+64i+8*t3+t0 (thread [P3P1P0], i=P2) -> stages 6..8
//   L4: p = 512i + t        (thread [P2P1P0], i=P3) -> stages 9..11 + store
//
// Transitions via 32 KB LDS (float2[4096] = row-PAIR packed, 2 passes each):
//   T1 (P0<->P1) and T2 (P1<->P2): writer & reader share wave digit P3, and
//   slot regions are per-wave disjoint -> INTRA-WAVE: no __syncthreads, only
//   an lgkmcnt(0) fence (DS ops are in-order per wave). vmem prefetches of W
//   survive these transitions un-drained.
//   T3 (P2<->P3): cross-wave -> 3 x __syncthreads.
//
// Swizzle slot(P3,P2,P1,P0): bank bits b0..2 = P0^P1^P2, b3 = P1[0]^P2[1].
// Bijective (U = [P3|P2|P1>>1] recovers everything), and bank-optimal
// (4 lanes per bank-pair = the wave64 b64 floor) for ALL six access patterns:
//   T1w vary{P2,P1}, T1r/T2w vary{P2,P0}, T2r/T3w vary{P1,P0}, T3r vary{P1,P0}.
//
// Occupancy: 32 KB LDS -> 4 blocks/CU (128 KB) x 8 waves = 32 waves/CU = 100%,
// VGPR 64 -> 8 waves/SIMD. Round 0 was 21%.

constexpr int LROW = 4096;
constexpr int RPB  = 4;
constexpr int NBLK = 8192 / RPB;   // 2048 blocks x 512 threads

__device__ __forceinline__ int slotf(int P3, int P2, int P1, int P0) {
    const int b012 = (P0 ^ P1 ^ P2) & 7;
    const int b3   = (P1 ^ (P2 >> 1)) & 1;
    const int U    = (P3 << 5) | (P2 << 2) | (P1 >> 1);
    return (U << 4) | (b3 << 3) | b012;
}

__global__ __launch_bounds__(512)
void butterfly12_kernel(const float* __restrict__ x,
                        const float* __restrict__ W,
                        float* __restrict__ out)
{
    __shared__ float2 lds[LROW];   // 32 KB

    const int t  = threadIdx.x;    // 9 bits
    const int t6 = t >> 6;         // wave id
    const int t3 = (t >> 3) & 7;
    const int t0 = t & 7;
    const size_t row0 = (size_t)blockIdx.x * RPB;

    float v[RPB][8];

    // ---- load: L1, p = 8t + i, 2 x float4 per row ----
    #pragma unroll
    for (int r = 0; r < RPB; ++r) {
        const float4* xr = reinterpret_cast<const float4*>(x + (row0 + r) * LROW + 8 * t);
        const float4 qa = xr[0], qb = xr[1];
        v[r][0]=qa.x; v[r][1]=qa.y; v[r][2]=qa.z; v[r][3]=qa.w;
        v[r][4]=qb.x; v[r][5]=qb.y; v[r][6]=qb.z; v[r][7]=qb.w;
    }

    // ---- phase A: stages 0..2 on digit P0 ----
    {   // stage 0: adjacent pairs -> float4 weight loads
        const float* w0 = W + ((size_t)0 * LROW + 8 * t) * 2;
        #pragma unroll
        for (int g = 0; g < 8; g += 2) {
            const float4 q = *reinterpret_cast<const float4*>(w0 + 2 * g);
            #pragma unroll
            for (int r = 0; r < RPB; ++r) {
                const float va = v[r][g], vb = v[r][g+1];
                v[r][g]   = q.x * va + q.y * vb;
                v[r][g+1] = q.z * vb + q.w * va;
            }
        }
    }
    #pragma unroll
    for (int b = 1; b < 3; ++b) {
        const float* wb = W + ((size_t)b * LROW + 8 * t) * 2;
        const int dl = 1 << b;
        #pragma unroll
        for (int g = 0; g < 8; g += 2*dl)
            #pragma unroll
            for (int m = 0; m < dl; ++m) {
                const int a = g + m, c = a + dl;
                const float2 wa = *reinterpret_cast<const float2*>(wb + 2*a);
                const float2 wc = *reinterpret_cast<const float2*>(wb + 2*c);
                #pragma unroll
                for (int r = 0; r < RPB; ++r) {
                    const float va = v[r][a], vb = v[r][c];
                    v[r][a] = wa.x * va + wa.y * vb;
                    v[r][c] = wc.x * vb + wc.y * va;
                }
            }
    }

    // ---- T1: L1 -> L2 (intra-wave, per-wave disjoint slot regions) ----
    #pragma unroll
    for (int h = 0; h < 2; ++h) {
        asm volatile("" ::: "memory");                       // keep pass order
        #pragma unroll
        for (int i = 0; i < 8; ++i)
            lds[slotf(t6, t3, t0, i)] = make_float2(v[2*h][i], v[2*h+1][i]);
        asm volatile("s_waitcnt lgkmcnt(0)" ::: "memory");   // writes visible
        #pragma unroll
        for (int j = 0; j < 8; ++j) {
            const float2 q = lds[slotf(t6, t3, j, t0)];
            v[2*h][j] = q.x; v[2*h+1][j] = q.y;
        }
    }

    // ---- phase B: stages 3..5 on digit P1 ----
    #pragma unroll
    for (int b = 0; b < 3; ++b) {
        const float* wb = W + ((size_t)(3 + b) * LROW + t6*512 + t3*64 + t0) * 2;
        const int dl = 1 << b;
        #pragma unroll
        for (int g = 0; g < 8; g += 2*dl)
            #pragma unroll
            for (int m = 0; m < dl; ++m) {
                const int a = g + m, c = a + dl;
                const float2 wa = *reinterpret_cast<const float2*>(wb + 16*a);
                const float2 wc = *reinterpret_cast<const float2*>(wb + 16*c);
                #pragma unroll
                for (int r = 0; r < RPB; ++r) {
                    const float va = v[r][a], vb = v[r][c];
                    v[r][a] = wa.x * va + wa.y * vb;
                    v[r][c] = wc.x * vb + wc.y * va;
                }
            }
    }

    // ---- T2: L2 -> L3 (intra-wave; writes reuse this thread's T1-read slots) ----
    #pragma unroll
    for (int h = 0; h < 2; ++h) {
        asm volatile("" ::: "memory");
        #pragma unroll
        for (int j = 0; j < 8; ++j)
            lds[slotf(t6, t3, j, t0)] = make_float2(v[2*h][j], v[2*h+1][j]);
        asm volatile("s_waitcnt lgkmcnt(0)" ::: "memory");
        #pragma unroll
        for (int k = 0; k < 8; ++k) {
            const float2 q = lds[slotf(t6, k, t3, t0)];
            v[2*h][k] = q.x; v[2*h+1][k] = q.y;
        }
    }

    // ---- phase C: stages 6..8 on digit P2 ----
    #pragma unroll
    for (int b = 0; b < 3; ++b) {
        const float* wb = W + ((size_t)(6 + b) * LROW + t6*512 + t3*8 + t0) * 2;
        const int dl = 1 << b;
        #pragma unroll
        for (int g = 0; g < 8; g += 2*dl)
            #pragma unroll
            for (int m = 0; m < dl; ++m) {
                const int a = g + m, c = a + dl;
                const float2 wa = *reinterpret_cast<const float2*>(wb + 128*a);
                const float2 wc = *reinterpret_cast<const float2*>(wb + 128*c);
                #pragma unroll
                for (int r = 0; r < RPB; ++r) {
                    const float va = v[r][a], vb = v[r][c];
                    v[r][a] = wa.x * va + wa.y * vb;
                    v[r][c] = wc.x * vb + wc.y * va;
                }
            }
    }

    // ---- T3: L3 -> L4 (cross-wave: P2 <-> P3) ----
    {
        #pragma unroll
        for (int k = 0; k < 8; ++k)     // writes reuse this thread's T2-read slots
            lds[slotf(t6, k, t3, t0)] = make_float2(v[0][k], v[1][k]);
        __syncthreads();
        #pragma unroll
        for (int m = 0; m < 8; ++m) {
            const float2 q = lds[slotf(m, t6, t3, t0)];
            v[0][m] = q.x; v[1][m] = q.y;
        }
        __syncthreads();                // all pass-1 reads done before overwrite
        #pragma unroll
        for (int k = 0; k < 8; ++k)
            lds[slotf(t6, k, t3, t0)] = make_float2(v[2][k], v[3][k]);
        __syncthreads();
        #pragma unroll
        for (int m = 0; m < 8; ++m) {
            const float2 q = lds[slotf(m, t6, t3, t0)];
            v[2][m] = q.x; v[3][m] = q.y;
        }
    }

    // ---- phase D: stages 9..11 on digit P3 ----
    #pragma unroll
    for (int b = 0; b < 3; ++b) {
        const float* wb = W + ((size_t)(9 + b) * LROW + t) * 2;
        const int dl = 1 << b;
        #pragma unroll
        for (int g = 0; g < 8; g += 2*dl)
            #pragma unroll
            for (int m = 0; m < dl; ++m) {
                const int a = g + m, c = a + dl;
                const float2 wa = *reinterpret_cast<const float2*>(wb + 1024*a);
                const float2 wc = *reinterpret_cast<const float2*>(wb + 1024*c);
                #pragma unroll
                for (int r = 0; r < RPB; ++r) {
                    const float va = v[r][a], vb = v[r][c];
                    v[r][a] = wa.x * va + wa.y * vb;
                    v[r][c] = wc.x * vb + wc.y * va;
                }
            }
    }

    // ---- store: L4, p = 512m + t => fully coalesced dword stores ----
    #pragma unroll
    for (int r = 0; r < RPB; ++r) {
        float* orow = out + (row0 + r) * LROW;
        #pragma unroll
        for (int m = 0; m < 8; ++m)
            orow[m*512 + t] = v[r][m];
    }
}

extern "C" void kernel_launch(void* const* d_in, const int* in_sizes, int n_in,
                              void* d_out, int out_size, void* d_ws, size_t ws_size,
                              hipStream_t stream) {
    const float* x = (const float*)d_in[0];   // (8192, 4096) fp32
    const float* W = (const float*)d_in[1];   // (12, 4096, 2) fp32
    float* out = (float*)d_out;               // (8192, 4096) fp32

    butterfly12_kernel<<<NBLK, 512, 0, stream>>>(x, W, out);
}